// Round 8
// baseline (351.814 us; speedup 1.0000x reference)
//
#include <hip/hip_runtime.h>
#include <math.h>

#define NEG_SLOPE 0.2f
#define POOL_CHUNKS 8

typedef __attribute__((ext_vector_type(8))) short bf16x8;
typedef __attribute__((ext_vector_type(4))) float f32x4;

__device__ __forceinline__ void split_bf16(float x, short& hi, short& lo) {
    unsigned u = __float_as_uint(x);
    unsigned uh = u & 0xFFFF0000u;
    float r = x - __uint_as_float(uh);
    hi = (short)(uh >> 16);
    lo = (short)(__float_as_uint(r) >> 16);
}

__device__ __forceinline__ unsigned f2bf_rne(float x) {
    unsigned u = __float_as_uint(x);
    return (u + 0x7fffu + ((u >> 16) & 1u)) >> 16;
}

// ---------------- node GEMM via split-bf16 MFMA ------------------------------
__global__ __launch_bounds__(256, 1) void node_gemm(
    const float* __restrict__ h, const float* __restrict__ Wl,
    const float* __restrict__ Wr, unsigned* __restrict__ xlb,
    float* __restrict__ xr, int N, int nTiles)
{
    const int w   = threadIdx.x >> 6;
    const int l   = threadIdx.x & 63;
    const int l15 = l & 15, lg = l >> 4;

    const float* __restrict__ Wsel = (w < 2) ? Wl : Wr;
    const int cbase = (w & 1) * 64;

    bf16x8 bh[4][4], bl_[4][4];
    #pragma unroll
    for (int ct = 0; ct < 4; ++ct) {
        const int c = cbase + ct * 16 + l15;
        #pragma unroll
        for (int kt = 0; kt < 4; ++kt) {
            #pragma unroll
            for (int i = 0; i < 8; ++i) {
                float v = Wsel[(kt * 32 + lg * 8 + i) * 128 + c];
                short hi, lo; split_bf16(v, hi, lo);
                bh[ct][kt][i] = hi; bl_[ct][kt][i] = lo;
            }
        }
    }

    for (int tile = blockIdx.x; tile < nTiles; tile += gridDim.x) {
        const int row0 = tile * 64;

        f32x4 acc[4][4];
        #pragma unroll
        for (int rt = 0; rt < 4; ++rt)
            #pragma unroll
            for (int ct = 0; ct < 4; ++ct)
                acc[rt][ct] = (f32x4){0.f, 0.f, 0.f, 0.f};

        #pragma unroll
        for (int rt = 0; rt < 4; ++rt) {
            int row = row0 + rt * 16 + l15;
            int rowc = row < N ? row : N - 1;
            bf16x8 ah[4], al[4];
            #pragma unroll
            for (int kt = 0; kt < 4; ++kt) {
                const float4 v0 = *(const float4*)&h[(size_t)rowc * 128 + kt * 32 + lg * 8];
                const float4 v1 = *(const float4*)&h[(size_t)rowc * 128 + kt * 32 + lg * 8 + 4];
                const float vv[8] = {v0.x, v0.y, v0.z, v0.w, v1.x, v1.y, v1.z, v1.w};
                #pragma unroll
                for (int i = 0; i < 8; ++i) {
                    short hi, lo; split_bf16(vv[i], hi, lo);
                    ah[kt][i] = hi; al[kt][i] = lo;
                }
            }
            #pragma unroll
            for (int kt = 0; kt < 4; ++kt) {
                #pragma unroll
                for (int ct = 0; ct < 4; ++ct) {
                    acc[rt][ct] = __builtin_amdgcn_mfma_f32_16x16x32_bf16(
                        ah[kt], bh[ct][kt], acc[rt][ct], 0, 0, 0);
                    acc[rt][ct] = __builtin_amdgcn_mfma_f32_16x16x32_bf16(
                        al[kt], bh[ct][kt], acc[rt][ct], 0, 0, 0);
                    acc[rt][ct] = __builtin_amdgcn_mfma_f32_16x16x32_bf16(
                        ah[kt], bl_[ct][kt], acc[rt][ct], 0, 0, 0);
                }
            }
        }

        if (w < 2) {
            #pragma unroll
            for (int rt = 0; rt < 4; ++rt) {
                #pragma unroll
                for (int ct = 0; ct < 4; ++ct) {
                    #pragma unroll
                    for (int j = 0; j < 4; ++j) {
                        int row = row0 + rt * 16 + lg * 4 + j;
                        unsigned o = f2bf_rne(acc[rt][ct][j]);
                        unsigned pr = (unsigned)__shfl_xor((int)o, 1);
                        if (!(l15 & 1) && row < N) {
                            int cp = (cbase + ct * 16 + l15) >> 1;
                            xlb[(size_t)row * 64 + cp] = o | (pr << 16);
                        }
                    }
                }
            }
        } else {
            #pragma unroll
            for (int rt = 0; rt < 4; ++rt) {
                #pragma unroll
                for (int ct = 0; ct < 4; ++ct) {
                    #pragma unroll
                    for (int j = 0; j < 4; ++j) {
                        int row = row0 + rt * 16 + lg * 4 + j;
                        if (row < N)
                            xr[(size_t)row * 128 + cbase + ct * 16 + l15] = acc[rt][ct][j];
                    }
                }
            }
        }
    }
}

// ---------------- CSR build (counting sort by dst) ---------------------------
__global__ __launch_bounds__(256) void edge_hist(
    const int* __restrict__ ei, int* __restrict__ deg, int E, int ET)
{
    int eid = blockIdx.x * blockDim.x + threadIdx.x;
    if (eid >= ET) return;
    int dst = (eid < E) ? ei[E + eid] : eid - E;
    atomicAdd(&deg[dst], 1);
}

__global__ __launch_bounds__(256) void scan_block(
    const int* __restrict__ in, int* __restrict__ out_excl,
    int* __restrict__ bsum, int N)
{
    __shared__ int sm[256];
    int t = threadIdx.x, i = blockIdx.x * 256 + t;
    int v = (i < N) ? in[i] : 0;
    sm[t] = v;
    __syncthreads();
    int x = v;
    for (int o = 1; o < 256; o <<= 1) {
        int u = (t >= o) ? sm[t - o] : 0;
        __syncthreads();
        x += u; sm[t] = x;
        __syncthreads();
    }
    if (i < N) out_excl[i] = x - v;
    if (t == 255) bsum[blockIdx.x] = x;
}

__global__ __launch_bounds__(256) void scan_sums(int* __restrict__ bsum, int nb)
{
    __shared__ int sm[256];
    int t = threadIdx.x;
    int v = (t < nb) ? bsum[t] : 0;
    sm[t] = v;
    __syncthreads();
    int x = v;
    for (int o = 1; o < 256; o <<= 1) {
        int u = (t >= o) ? sm[t - o] : 0;
        __syncthreads();
        x += u; sm[t] = x;
        __syncthreads();
    }
    if (t < nb) bsum[t] = x - v;
}

__global__ __launch_bounds__(256) void scan_final(
    const int* __restrict__ excl, const int* __restrict__ bsum,
    int* __restrict__ rowptr, int N, int ET)
{
    int i = blockIdx.x * blockDim.x + threadIdx.x;
    if (i > N) return;
    rowptr[i] = (i < N) ? (excl[i] + bsum[i >> 8]) : ET;
}

__global__ __launch_bounds__(256) void edge_fill(
    const int* __restrict__ ei, const int* __restrict__ rowptr,
    int* __restrict__ cursor, int* __restrict__ srcs, int E, int ET)
{
    int eid = blockIdx.x * blockDim.x + threadIdx.x;
    if (eid >= ET) return;
    int src, dst;
    if (eid < E) { src = ei[eid]; dst = ei[E + eid]; }
    else { src = dst = eid - E; }
    int pos = rowptr[dst] + atomicAdd(&cursor[dst], 1);
    srcs[pos] = src;
}

// ---------------- fused GATv2 aggregate --------------------------------------
// one wave per dst node; four 16-lane groups, stride-4 edges, 4-edge unroll:
// 4 independent gathers + 4 interleaved shuffle chains in flight per group.
__global__ __launch_bounds__(256) void gatv2_aggregate(
    const unsigned* __restrict__ xlb, const float* __restrict__ xr,
    const int* __restrict__ rowptr, const int* __restrict__ srcs,
    const float* __restrict__ att, const float* __restrict__ b,
    float* __restrict__ hout, int N, int do_relu, int nQuads)
{
    const int lane = threadIdx.x & 63;
    const int wv = threadIdx.x >> 6;
    const int hl = lane & 15;     // lane within 16-lane group
    const int g  = lane >> 4;     // group id 0..3

    float at8[8];
    {
        const float4 t0 = *(const float4*)&att[hl * 8];
        const float4 t1 = *(const float4*)&att[hl * 8 + 4];
        at8[0]=t0.x; at8[1]=t0.y; at8[2]=t0.z; at8[3]=t0.w;
        at8[4]=t1.x; at8[5]=t1.y; at8[6]=t1.z; at8[7]=t1.w;
    }

    for (int q = blockIdx.x; q < nQuads; q += gridDim.x) {
        const int n = q * 4 + wv;
        if (n >= N) continue;

        float xr8[8];
        {
            const float4 a0 = *(const float4*)&xr[(size_t)n * 128 + hl * 8];
            const float4 a1 = *(const float4*)&xr[(size_t)n * 128 + hl * 8 + 4];
            xr8[0]=a0.x; xr8[1]=a0.y; xr8[2]=a0.z; xr8[3]=a0.w;
            xr8[4]=a1.x; xr8[5]=a1.y; xr8[6]=a1.z; xr8[7]=a1.w;
        }

        int r0 = rowptr[n], r1 = rowptr[n + 1];
        float m = -INFINITY, s = 0.f;
        float acc[8];
        #pragma unroll
        for (int c = 0; c < 8; ++c) acc[c] = 0.f;

        auto unpack = [&](const uint4 q4, float* vv) {
            unsigned u;
            u = q4.x; vv[0] = __uint_as_float(u << 16); vv[1] = __uint_as_float(u & 0xFFFF0000u);
            u = q4.y; vv[2] = __uint_as_float(u << 16); vv[3] = __uint_as_float(u & 0xFFFF0000u);
            u = q4.z; vv[4] = __uint_as_float(u << 16); vv[5] = __uint_as_float(u & 0xFFFF0000u);
            u = q4.w; vv[6] = __uint_as_float(u << 16); vv[7] = __uint_as_float(u & 0xFFFF0000u);
        };
        auto score = [&](const float* vv) -> float {
            float p = 0.f;
            #pragma unroll
            for (int c = 0; c < 8; ++c) {
                float t = vv[c] + xr8[c];
                t = fmaxf(t, NEG_SLOPE * t);
                p += t * at8[c];
            }
            return p;
        };
        auto online1 = [&](float p, const float* vv) {
            float mn = fmaxf(m, p);
            float f = __expf(m - mn);
            float w = __expf(p - mn);
            s = s * f + w;
            #pragma unroll
            for (int c = 0; c < 8; ++c) acc[c] = acc[c] * f + w * vv[c];
            m = mn;
        };

        int j = r0 + g;
        // main: 4 edges per group per iteration (16 per wave)
        for (; j + 12 < r1; j += 16) {
            int sa = srcs[j], sb = srcs[j + 4], sc = srcs[j + 8], sd = srcs[j + 12];
            const uint4 qa = *(const uint4*)&xlb[(size_t)sa * 64 + hl * 4];
            const uint4 qb = *(const uint4*)&xlb[(size_t)sb * 64 + hl * 4];
            const uint4 qc = *(const uint4*)&xlb[(size_t)sc * 64 + hl * 4];
            const uint4 qd = *(const uint4*)&xlb[(size_t)sd * 64 + hl * 4];
            float va[8], vb[8], vc[8], vd[8];
            unpack(qa, va); unpack(qb, vb); unpack(qc, vc); unpack(qd, vd);
            float p0 = score(va), p1 = score(vb), p2 = score(vc), p3 = score(vd);
            #pragma unroll
            for (int off = 1; off < 16; off <<= 1) {
                p0 += __shfl_xor(p0, off);
                p1 += __shfl_xor(p1, off);
                p2 += __shfl_xor(p2, off);
                p3 += __shfl_xor(p3, off);
            }
            // combine 4 edges locally, then one merged rescale
            float m4 = fmaxf(fmaxf(p0, p1), fmaxf(p2, p3));
            float w0 = __expf(p0 - m4), w1 = __expf(p1 - m4);
            float w2 = __expf(p2 - m4), w3 = __expf(p3 - m4);
            float s4 = (w0 + w1) + (w2 + w3);
            float mn = fmaxf(m, m4);
            float f  = __expf(m - mn);    // first iter: exp(-inf)=0
            float gw = __expf(m4 - mn);
            s = s * f + s4 * gw;
            w0 *= gw; w1 *= gw; w2 *= gw; w3 *= gw;
            #pragma unroll
            for (int c = 0; c < 8; ++c)
                acc[c] = acc[c] * f + w0 * va[c] + w1 * vb[c] + w2 * vc[c] + w3 * vd[c];
            m = mn;
        }
        // tail: up to 3 edges per group
        for (; j < r1; j += 4) {
            int sa = srcs[j];
            const uint4 qa = *(const uint4*)&xlb[(size_t)sa * 64 + hl * 4];
            float va[8];
            unpack(qa, va);
            float pa = score(va);
            #pragma unroll
            for (int off = 1; off < 16; off <<= 1) pa += __shfl_xor(pa, off);
            online1(pa, va);
        }

        // merge the 4 group states
        float mm = m;
        mm = fmaxf(mm, __shfl_xor(mm, 16));
        mm = fmaxf(mm, __shfl_xor(mm, 32));
        float f = __expf(m - mm);            // empty group: m=-inf -> f=0
        s *= f;
        #pragma unroll
        for (int c = 0; c < 8; ++c) acc[c] *= f;
        s += __shfl_xor(s, 16); s += __shfl_xor(s, 32);
        #pragma unroll
        for (int c = 0; c < 8; ++c) {
            acc[c] += __shfl_xor(acc[c], 16);
            acc[c] += __shfl_xor(acc[c], 32);
        }

        if (g == 0) {
            float inv = 1.f / s;
            float o[8];
            #pragma unroll
            for (int c = 0; c < 8; ++c) {
                o[c] = acc[c] * inv + b[hl * 8 + c];
                if (do_relu) o[c] = fmaxf(o[c], 0.f);
            }
            *(float4*)&hout[(size_t)n * 128 + hl * 8]     = make_float4(o[0], o[1], o[2], o[3]);
            *(float4*)&hout[(size_t)n * 128 + hl * 8 + 4] = make_float4(o[4], o[5], o[6], o[7]);
        }
    }
}

// ---------------- pooling ----------------------------------------------------
__global__ __launch_bounds__(256) void graph_bounds(
    const int* __restrict__ batch, int* __restrict__ gstart, int N, int B)
{
    int b = blockIdx.x * blockDim.x + threadIdx.x;
    if (b > B) return;
    int lo = 0, hi = N;
    while (lo < hi) {
        int mid = (lo + hi) >> 1;
        if (batch[mid] < b) lo = mid + 1; else hi = mid;
    }
    gstart[b] = lo;
}

__global__ __launch_bounds__(256) void pool_graph(
    const float* __restrict__ h, const int* __restrict__ gstart,
    float* __restrict__ pooled)
{
    __shared__ float sm[128];
    const int b = blockIdx.x / POOL_CHUNKS;
    const int chunk = blockIdx.x % POOL_CHUNKS;
    const int t = threadIdx.x;
    const int col = t & 127, hf = t >> 7;
    const int r0 = gstart[b], r1 = gstart[b + 1];
    const int len = r1 - r0;
    const int c0 = r0 + (int)(((long long)len * chunk) / POOL_CHUNKS);
    const int c1 = r0 + (int)(((long long)len * (chunk + 1)) / POOL_CHUNKS);
    float s = 0.f;
    for (int r = c0 + hf; r < c1; r += 2)
        s += h[(size_t)r * 128 + col];
    if (hf) sm[col] = s;
    __syncthreads();
    if (!hf) atomicAdd(&pooled[b * 128 + col], s + sm[col]);
}

// ---------------- MLP head ---------------------------------------------------
__global__ __launch_bounds__(256) void mlp_head(
    const float* __restrict__ pooled, const int* __restrict__ gstart,
    const int* __restrict__ day, const int* __restrict__ hour,
    const float* __restrict__ day_tab, const float* __restrict__ hour_tab,
    const float* __restrict__ W1, const float* __restrict__ bl1,
    const float* __restrict__ W2, const float* __restrict__ bl2,
    const float* __restrict__ W3, const float* __restrict__ bl3,
    float* __restrict__ out)
{
    __shared__ float f0[256], f1[256];
    const int b = blockIdx.x, t = threadIdx.x;
    float c = fmaxf((float)(gstart[b + 1] - gstart[b]), 1.f);
    if (t < 128)      f0[t] = pooled[b * 128 + t] / c;
    else if (t < 192) f0[t] = day_tab[day[b] * 64 + (t - 128)];
    else              f0[t] = hour_tab[hour[b] * 64 + (t - 192)];
    __syncthreads();
    float a = bl1[t];
    for (int k = 0; k < 256; ++k) a += f0[k] * W1[k * 256 + t];
    f1[t] = a > 0.f ? a : 0.f;
    __syncthreads();
    a = bl2[t];
    for (int k = 0; k < 256; ++k) a += f1[k] * W2[k * 256 + t];
    __syncthreads();
    f0[t] = a > 0.f ? a : 0.f;
    __syncthreads();
    f1[t] = f0[t] * W3[t];
    __syncthreads();
    for (int s2 = 128; s2 > 0; s2 >>= 1) {
        if (t < s2) f1[t] += f1[t + s2];
        __syncthreads();
    }
    if (t == 0) out[b] = f1[0] + bl3[0];
}

extern "C" void kernel_launch(void* const* d_in, const int* in_sizes, int n_in,
                              void* d_out, int out_size, void* d_ws, size_t ws_size,
                              hipStream_t stream) {
    const float* x        = (const float*)d_in[0];
    const int*   ei       = (const int*)d_in[1];
    const int*   batch    = (const int*)d_in[2];
    const int*   day      = (const int*)d_in[3];
    const int*   hour     = (const int*)d_in[4];
    const float* Wl[3]  = { (const float*)d_in[5],  (const float*)d_in[9],  (const float*)d_in[13] };
    const float* Wr[3]  = { (const float*)d_in[6],  (const float*)d_in[10], (const float*)d_in[14] };
    const float* att[3] = { (const float*)d_in[7],  (const float*)d_in[11], (const float*)d_in[15] };
    const float* bb[3]  = { (const float*)d_in[8],  (const float*)d_in[12], (const float*)d_in[16] };
    const float* day_tab  = (const float*)d_in[17];
    const float* hour_tab = (const float*)d_in[18];
    const float* W1 = (const float*)d_in[19]; const float* bl1 = (const float*)d_in[20];
    const float* W2 = (const float*)d_in[21]; const float* bl2 = (const float*)d_in[22];
    const float* W3 = (const float*)d_in[23]; const float* bl3 = (const float*)d_in[24];
    float* out = (float*)d_out;

    const int N  = in_sizes[0] / 128;
    const int E  = in_sizes[1] / 2;
    const int B  = in_sizes[3];
    const int ET = E + N;

    char* ws = (char*)d_ws;
    size_t off = 0;
    auto alloc = [&](size_t bytes) -> void* {
        void* p = ws + off;
        off += (bytes + 255) & ~(size_t)255;
        return p;
    };
    const size_t NB = (size_t)N * 128 * sizeof(float);
    unsigned* xlb = (unsigned*)alloc((size_t)N * 64 * sizeof(unsigned));
    float* xr     = (float*)alloc(NB);
    float* hbuf   = (float*)alloc(NB);
    int*   deg    = (int*)alloc((size_t)N * sizeof(int));
    int*   excl   = (int*)alloc((size_t)N * sizeof(int));
    int*   bsum   = (int*)alloc(256 * sizeof(int));
    int*   rowptr = (int*)alloc((size_t)(N + 1) * sizeof(int));
    int*   cursor = (int*)alloc((size_t)N * sizeof(int));
    int*   srcs   = (int*)alloc((size_t)ET * sizeof(int));
    int*   gstart = (int*)alloc((size_t)(B + 1) * sizeof(int));
    float* pooled = (float*)alloc((size_t)B * 128 * sizeof(float));
    (void)ws_size;

    const int nb = (N + 255) / 256;
    const int edge_grid  = (ET + 255) / 256;
    const int nQuads     = (N + 3) / 4;
    const int agg_grid   = nQuads < 2560 ? nQuads : 2560;
    const int nTiles     = (N + 63) / 64;
    const int gemm_grid  = (nTiles + 1) / 2;   // 2 row-tiles per block

    // ---- CSR build ----
    hipMemsetAsync(deg, 0, (size_t)N * sizeof(int), stream);
    hipMemsetAsync(cursor, 0, (size_t)N * sizeof(int), stream);
    edge_hist<<<edge_grid, 256, 0, stream>>>(ei, deg, E, ET);
    scan_block<<<nb, 256, 0, stream>>>(deg, excl, bsum, N);
    scan_sums<<<1, 256, 0, stream>>>(bsum, nb);
    scan_final<<<(N + 256) / 256, 256, 0, stream>>>(excl, bsum, rowptr, N, ET);
    edge_fill<<<edge_grid, 256, 0, stream>>>(ei, rowptr, cursor, srcs, E, ET);

    // ---- 3 GATv2 layers ----
    const float* hin = x;
    for (int l = 0; l < 3; ++l) {
        node_gemm<<<gemm_grid, 256, 0, stream>>>(hin, Wl[l], Wr[l], xlb, xr, N, nTiles);
        gatv2_aggregate<<<agg_grid, 256, 0, stream>>>(
            xlb, xr, rowptr, srcs, att[l], bb[l], hbuf, N, l < 2 ? 1 : 0, nQuads);
        hin = hbuf;
    }

    // ---- pool + head ----
    graph_bounds<<<1, 256, 0, stream>>>(batch, gstart, N, B);
    hipMemsetAsync(pooled, 0, (size_t)B * 128 * sizeof(float), stream);
    pool_graph<<<B * POOL_CHUNKS, 256, 0, stream>>>(hbuf, gstart, pooled);
    mlp_head<<<B, 256, 0, stream>>>(pooled, gstart, day, hour, day_tab, hour_tab,
                                    W1, bl1, W2, bl2, W3, bl3, out);
}

// Round 9
// 297.055 us; speedup vs baseline: 1.1843x; 1.1843x over previous
//
#include <hip/hip_runtime.h>
#include <math.h>

#define NEG_SLOPE 0.2f
#define POOL_CHUNKS 8

typedef __attribute__((ext_vector_type(8))) short bf16x8;
typedef __attribute__((ext_vector_type(4))) float f32x4;

__device__ __forceinline__ void split_bf16(float x, short& hi, short& lo) {
    unsigned u = __float_as_uint(x);
    unsigned uh = u & 0xFFFF0000u;
    float r = x - __uint_as_float(uh);
    hi = (short)(uh >> 16);
    lo = (short)(__float_as_uint(r) >> 16);
}

__device__ __forceinline__ unsigned f2bf_rne(float x) {
    unsigned u = __float_as_uint(x);
    return (u + 0x7fffu + ((u >> 16) & 1u)) >> 16;
}

// ---------------- node GEMM via split-bf16 MFMA ------------------------------
// C[M][256] = h[M][128] @ [Wl|Wr][128][256].
// cols 0-127 -> xlb (PACKED bf16 pairs, u32 [N][64]); cols 128-255 -> xr (f32).
// 1 row-tile (64 rows) per block, 625 blocks; B (hi+lo) in registers.
__global__ __launch_bounds__(256, 1) void node_gemm(
    const float* __restrict__ h, const float* __restrict__ Wl,
    const float* __restrict__ Wr, unsigned* __restrict__ xlb,
    float* __restrict__ xr, int N, int nTiles)
{
    const int w   = threadIdx.x >> 6;
    const int l   = threadIdx.x & 63;
    const int l15 = l & 15, lg = l >> 4;

    const float* __restrict__ Wsel = (w < 2) ? Wl : Wr;
    const int cbase = (w & 1) * 64;

    bf16x8 bh[4][4], bl_[4][4];
    #pragma unroll
    for (int ct = 0; ct < 4; ++ct) {
        const int c = cbase + ct * 16 + l15;
        #pragma unroll
        for (int kt = 0; kt < 4; ++kt) {
            #pragma unroll
            for (int i = 0; i < 8; ++i) {
                float v = Wsel[(kt * 32 + lg * 8 + i) * 128 + c];
                short hi, lo; split_bf16(v, hi, lo);
                bh[ct][kt][i] = hi; bl_[ct][kt][i] = lo;
            }
        }
    }

    for (int tile = blockIdx.x; tile < nTiles; tile += gridDim.x) {
        const int row0 = tile * 64;

        f32x4 acc[4][4];
        #pragma unroll
        for (int rt = 0; rt < 4; ++rt)
            #pragma unroll
            for (int ct = 0; ct < 4; ++ct)
                acc[rt][ct] = (f32x4){0.f, 0.f, 0.f, 0.f};

        #pragma unroll
        for (int rt = 0; rt < 4; ++rt) {
            int row = row0 + rt * 16 + l15;
            int rowc = row < N ? row : N - 1;
            bf16x8 ah[4], al[4];
            #pragma unroll
            for (int kt = 0; kt < 4; ++kt) {
                const float4 v0 = *(const float4*)&h[(size_t)rowc * 128 + kt * 32 + lg * 8];
                const float4 v1 = *(const float4*)&h[(size_t)rowc * 128 + kt * 32 + lg * 8 + 4];
                const float vv[8] = {v0.x, v0.y, v0.z, v0.w, v1.x, v1.y, v1.z, v1.w};
                #pragma unroll
                for (int i = 0; i < 8; ++i) {
                    short hi, lo; split_bf16(vv[i], hi, lo);
                    ah[kt][i] = hi; al[kt][i] = lo;
                }
            }
            #pragma unroll
            for (int kt = 0; kt < 4; ++kt) {
                #pragma unroll
                for (int ct = 0; ct < 4; ++ct) {
                    acc[rt][ct] = __builtin_amdgcn_mfma_f32_16x16x32_bf16(
                        ah[kt], bh[ct][kt], acc[rt][ct], 0, 0, 0);
                    acc[rt][ct] = __builtin_amdgcn_mfma_f32_16x16x32_bf16(
                        al[kt], bh[ct][kt], acc[rt][ct], 0, 0, 0);
                    acc[rt][ct] = __builtin_amdgcn_mfma_f32_16x16x32_bf16(
                        ah[kt], bl_[ct][kt], acc[rt][ct], 0, 0, 0);
                }
            }
        }

        if (w < 2) {
            #pragma unroll
            for (int rt = 0; rt < 4; ++rt) {
                #pragma unroll
                for (int ct = 0; ct < 4; ++ct) {
                    #pragma unroll
                    for (int j = 0; j < 4; ++j) {
                        int row = row0 + rt * 16 + lg * 4 + j;
                        unsigned o = f2bf_rne(acc[rt][ct][j]);
                        unsigned pr = (unsigned)__shfl_xor((int)o, 1);
                        if (!(l15 & 1) && row < N) {
                            int cp = (cbase + ct * 16 + l15) >> 1;
                            xlb[(size_t)row * 64 + cp] = o | (pr << 16);
                        }
                    }
                }
            }
        } else {
            #pragma unroll
            for (int rt = 0; rt < 4; ++rt) {
                #pragma unroll
                for (int ct = 0; ct < 4; ++ct) {
                    #pragma unroll
                    for (int j = 0; j < 4; ++j) {
                        int row = row0 + rt * 16 + lg * 4 + j;
                        if (row < N)
                            xr[(size_t)row * 128 + cbase + ct * 16 + l15] = acc[rt][ct][j];
                    }
                }
            }
        }
    }
}

// ---------------- CSR build (counting sort by dst) ---------------------------
__global__ __launch_bounds__(256) void edge_hist(
    const int* __restrict__ ei, int* __restrict__ deg, int E, int ET)
{
    int eid = blockIdx.x * blockDim.x + threadIdx.x;
    if (eid >= ET) return;
    int dst = (eid < E) ? ei[E + eid] : eid - E;
    atomicAdd(&deg[dst], 1);
}

__global__ __launch_bounds__(256) void scan_block(
    const int* __restrict__ in, int* __restrict__ out_excl,
    int* __restrict__ bsum, int N)
{
    __shared__ int sm[256];
    int t = threadIdx.x, i = blockIdx.x * 256 + t;
    int v = (i < N) ? in[i] : 0;
    sm[t] = v;
    __syncthreads();
    int x = v;
    for (int o = 1; o < 256; o <<= 1) {
        int u = (t >= o) ? sm[t - o] : 0;
        __syncthreads();
        x += u; sm[t] = x;
        __syncthreads();
    }
    if (i < N) out_excl[i] = x - v;
    if (t == 255) bsum[blockIdx.x] = x;
}

__global__ __launch_bounds__(256) void scan_sums(int* __restrict__ bsum, int nb)
{
    __shared__ int sm[256];
    int t = threadIdx.x;
    int v = (t < nb) ? bsum[t] : 0;
    sm[t] = v;
    __syncthreads();
    int x = v;
    for (int o = 1; o < 256; o <<= 1) {
        int u = (t >= o) ? sm[t - o] : 0;
        __syncthreads();
        x += u; sm[t] = x;
        __syncthreads();
    }
    if (t < nb) bsum[t] = x - v;
}

__global__ __launch_bounds__(256) void scan_final(
    const int* __restrict__ excl, const int* __restrict__ bsum,
    int* __restrict__ rowptr, int N, int ET)
{
    int i = blockIdx.x * blockDim.x + threadIdx.x;
    if (i > N) return;
    rowptr[i] = (i < N) ? (excl[i] + bsum[i >> 8]) : ET;
}

__global__ __launch_bounds__(256) void edge_fill(
    const int* __restrict__ ei, const int* __restrict__ rowptr,
    int* __restrict__ cursor, int* __restrict__ srcs, int E, int ET)
{
    int eid = blockIdx.x * blockDim.x + threadIdx.x;
    if (eid >= ET) return;
    int src, dst;
    if (eid < E) { src = ei[eid]; dst = ei[E + eid]; }
    else { src = dst = eid - E; }
    int pos = rowptr[dst] + atomicAdd(&cursor[dst], 1);
    srcs[pos] = src;
}

// ---------------- fused GATv2 aggregate --------------------------------------
// one wave per dst node; four 16-lane groups, stride-4 edges, 2-edge unroll,
// next-pair src-index software prefetch (clamped, unconditional).
__global__ __launch_bounds__(256) void gatv2_aggregate(
    const unsigned* __restrict__ xlb, const float* __restrict__ xr,
    const int* __restrict__ rowptr, const int* __restrict__ srcs,
    const float* __restrict__ att, const float* __restrict__ b,
    float* __restrict__ hout, int N, int do_relu)
{
    int n = blockIdx.x * 4 + (threadIdx.x >> 6);
    if (n >= N) return;
    const int lane = threadIdx.x & 63;
    const int hl = lane & 15;     // lane within 16-lane group
    const int g  = lane >> 4;     // group id 0..3

    float xr8[8], at8[8];
    {
        const float4 a0 = *(const float4*)&xr[(size_t)n * 128 + hl * 8];
        const float4 a1 = *(const float4*)&xr[(size_t)n * 128 + hl * 8 + 4];
        xr8[0]=a0.x; xr8[1]=a0.y; xr8[2]=a0.z; xr8[3]=a0.w;
        xr8[4]=a1.x; xr8[5]=a1.y; xr8[6]=a1.z; xr8[7]=a1.w;
        const float4 t0 = *(const float4*)&att[hl * 8];
        const float4 t1 = *(const float4*)&att[hl * 8 + 4];
        at8[0]=t0.x; at8[1]=t0.y; at8[2]=t0.z; at8[3]=t0.w;
        at8[4]=t1.x; at8[5]=t1.y; at8[6]=t1.z; at8[7]=t1.w;
    }

    int r0 = rowptr[n], r1 = rowptr[n + 1];
    float m = -INFINITY, s = 0.f;
    float acc[8];
    #pragma unroll
    for (int c = 0; c < 8; ++c) acc[c] = 0.f;

    auto unpack = [&](const uint4 q, float* vv) {
        unsigned u;
        u = q.x; vv[0] = __uint_as_float(u << 16); vv[1] = __uint_as_float(u & 0xFFFF0000u);
        u = q.y; vv[2] = __uint_as_float(u << 16); vv[3] = __uint_as_float(u & 0xFFFF0000u);
        u = q.z; vv[4] = __uint_as_float(u << 16); vv[5] = __uint_as_float(u & 0xFFFF0000u);
        u = q.w; vv[6] = __uint_as_float(u << 16); vv[7] = __uint_as_float(u & 0xFFFF0000u);
    };
    auto score = [&](const float* vv) -> float {
        float p = 0.f;
        #pragma unroll
        for (int c = 0; c < 8; ++c) {
            float t = vv[c] + xr8[c];
            t = fmaxf(t, NEG_SLOPE * t);
            p += t * at8[c];
        }
        return p;
    };
    auto online = [&](float p, const float* vv) {
        float mn = fmaxf(m, p);
        float f = __expf(m - mn);
        float w = __expf(p - mn);
        s = s * f + w;
        #pragma unroll
        for (int c = 0; c < 8; ++c) acc[c] = acc[c] * f + w * vv[c];
        m = mn;
    };

    int j = r0 + g;
    int sa = (j < r1) ? srcs[j] : 0;
    int sb = (j + 4 < r1) ? srcs[j + 4] : sa;
    for (; j + 4 < r1; j += 8) {
        const uint4 qa = *(const uint4*)&xlb[(size_t)sa * 64 + hl * 4];
        const uint4 qb = *(const uint4*)&xlb[(size_t)sb * 64 + hl * 4];
        // prefetch next pair's indices (clamped -> always safe, no branches)
        int jn0 = (j + 8  < r1) ? j + 8  : j;
        int jn1 = (j + 12 < r1) ? j + 12 : j;
        int sna = srcs[jn0], snb = srcs[jn1];
        float va[8], vb[8];
        unpack(qa, va); unpack(qb, vb);
        float pa = score(va), pb = score(vb);
        #pragma unroll
        for (int off = 1; off < 16; off <<= 1) {
            pa += __shfl_xor(pa, off);
            pb += __shfl_xor(pb, off);
        }
        online(pa, va);
        online(pb, vb);
        sa = sna; sb = snb;
    }
    if (j < r1) {
        const uint4 qa = *(const uint4*)&xlb[(size_t)sa * 64 + hl * 4];
        float va[8];
        unpack(qa, va);
        float pa = score(va);
        #pragma unroll
        for (int off = 1; off < 16; off <<= 1) pa += __shfl_xor(pa, off);
        online(pa, va);
    }

    // merge the 4 group states (cols identical at lanes l, l^16, l^32, l^48)
    float mm = m;
    mm = fmaxf(mm, __shfl_xor(mm, 16));
    mm = fmaxf(mm, __shfl_xor(mm, 32));
    float f = __expf(m - mm);            // empty group: m=-inf -> f=0
    s *= f;
    #pragma unroll
    for (int c = 0; c < 8; ++c) acc[c] *= f;
    s += __shfl_xor(s, 16); s += __shfl_xor(s, 32);
    #pragma unroll
    for (int c = 0; c < 8; ++c) {
        acc[c] += __shfl_xor(acc[c], 16);
        acc[c] += __shfl_xor(acc[c], 32);
    }

    if (g == 0) {
        float inv = 1.f / s;
        float o[8];
        #pragma unroll
        for (int c = 0; c < 8; ++c) {
            o[c] = acc[c] * inv + b[hl * 8 + c];
            if (do_relu) o[c] = fmaxf(o[c], 0.f);
        }
        *(float4*)&hout[(size_t)n * 128 + hl * 8]     = make_float4(o[0], o[1], o[2], o[3]);
        *(float4*)&hout[(size_t)n * 128 + hl * 8 + 4] = make_float4(o[4], o[5], o[6], o[7]);
    }
}

// ---------------- pooling ----------------------------------------------------
__global__ __launch_bounds__(256) void graph_bounds(
    const int* __restrict__ batch, int* __restrict__ gstart, int N, int B)
{
    int b = blockIdx.x * blockDim.x + threadIdx.x;
    if (b > B) return;
    int lo = 0, hi = N;
    while (lo < hi) {
        int mid = (lo + hi) >> 1;
        if (batch[mid] < b) lo = mid + 1; else hi = mid;
    }
    gstart[b] = lo;
}

__global__ __launch_bounds__(256) void pool_graph(
    const float* __restrict__ h, const int* __restrict__ gstart,
    float* __restrict__ pooled)
{
    __shared__ float sm[128];
    const int b = blockIdx.x / POOL_CHUNKS;
    const int chunk = blockIdx.x % POOL_CHUNKS;
    const int t = threadIdx.x;
    const int col = t & 127, hf = t >> 7;
    const int r0 = gstart[b], r1 = gstart[b + 1];
    const int len = r1 - r0;
    const int c0 = r0 + (int)(((long long)len * chunk) / POOL_CHUNKS);
    const int c1 = r0 + (int)(((long long)len * (chunk + 1)) / POOL_CHUNKS);
    float s = 0.f;
    for (int r = c0 + hf; r < c1; r += 2)
        s += h[(size_t)r * 128 + col];
    if (hf) sm[col] = s;
    __syncthreads();
    if (!hf) atomicAdd(&pooled[b * 128 + col], s + sm[col]);
}

// ---------------- MLP head ---------------------------------------------------
__global__ __launch_bounds__(256) void mlp_head(
    const float* __restrict__ pooled, const int* __restrict__ gstart,
    const int* __restrict__ day, const int* __restrict__ hour,
    const float* __restrict__ day_tab, const float* __restrict__ hour_tab,
    const float* __restrict__ W1, const float* __restrict__ bl1,
    const float* __restrict__ W2, const float* __restrict__ bl2,
    const float* __restrict__ W3, const float* __restrict__ bl3,
    float* __restrict__ out)
{
    __shared__ float f0[256], f1[256];
    const int b = blockIdx.x, t = threadIdx.x;
    float c = fmaxf((float)(gstart[b + 1] - gstart[b]), 1.f);
    if (t < 128)      f0[t] = pooled[b * 128 + t] / c;
    else if (t < 192) f0[t] = day_tab[day[b] * 64 + (t - 128)];
    else              f0[t] = hour_tab[hour[b] * 64 + (t - 192)];
    __syncthreads();
    float a = bl1[t];
    for (int k = 0; k < 256; ++k) a += f0[k] * W1[k * 256 + t];
    f1[t] = a > 0.f ? a : 0.f;
    __syncthreads();
    a = bl2[t];
    for (int k = 0; k < 256; ++k) a += f1[k] * W2[k * 256 + t];
    __syncthreads();
    f0[t] = a > 0.f ? a : 0.f;
    __syncthreads();
    f1[t] = f0[t] * W3[t];
    __syncthreads();
    for (int s2 = 128; s2 > 0; s2 >>= 1) {
        if (t < s2) f1[t] += f1[t + s2];
        __syncthreads();
    }
    if (t == 0) out[b] = f1[0] + bl3[0];
}

extern "C" void kernel_launch(void* const* d_in, const int* in_sizes, int n_in,
                              void* d_out, int out_size, void* d_ws, size_t ws_size,
                              hipStream_t stream) {
    const float* x        = (const float*)d_in[0];
    const int*   ei       = (const int*)d_in[1];
    const int*   batch    = (const int*)d_in[2];
    const int*   day      = (const int*)d_in[3];
    const int*   hour     = (const int*)d_in[4];
    const float* Wl[3]  = { (const float*)d_in[5],  (const float*)d_in[9],  (const float*)d_in[13] };
    const float* Wr[3]  = { (const float*)d_in[6],  (const float*)d_in[10], (const float*)d_in[14] };
    const float* att[3] = { (const float*)d_in[7],  (const float*)d_in[11], (const float*)d_in[15] };
    const float* bb[3]  = { (const float*)d_in[8],  (const float*)d_in[12], (const float*)d_in[16] };
    const float* day_tab  = (const float*)d_in[17];
    const float* hour_tab = (const float*)d_in[18];
    const float* W1 = (const float*)d_in[19]; const float* bl1 = (const float*)d_in[20];
    const float* W2 = (const float*)d_in[21]; const float* bl2 = (const float*)d_in[22];
    const float* W3 = (const float*)d_in[23]; const float* bl3 = (const float*)d_in[24];
    float* out = (float*)d_out;

    const int N  = in_sizes[0] / 128;
    const int E  = in_sizes[1] / 2;
    const int B  = in_sizes[3];
    const int ET = E + N;

    char* ws = (char*)d_ws;
    size_t off = 0;
    auto alloc = [&](size_t bytes) -> void* {
        void* p = ws + off;
        off += (bytes + 255) & ~(size_t)255;
        return p;
    };
    const size_t NB = (size_t)N * 128 * sizeof(float);
    unsigned* xlb = (unsigned*)alloc((size_t)N * 64 * sizeof(unsigned));
    float* xr     = (float*)alloc(NB);
    float* hbuf   = (float*)alloc(NB);
    int*   deg    = (int*)alloc((size_t)N * sizeof(int));
    int*   excl   = (int*)alloc((size_t)N * sizeof(int));
    int*   bsum   = (int*)alloc(256 * sizeof(int));
    int*   rowptr = (int*)alloc((size_t)(N + 1) * sizeof(int));
    int*   cursor = (int*)alloc((size_t)N * sizeof(int));
    int*   srcs   = (int*)alloc((size_t)ET * sizeof(int));
    int*   gstart = (int*)alloc((size_t)(B + 1) * sizeof(int));
    float* pooled = (float*)alloc((size_t)B * 128 * sizeof(float));
    (void)ws_size;

    const int nb = (N + 255) / 256;
    const int edge_grid  = (ET + 255) / 256;
    const int node_grid4 = (N + 3) / 4;
    const int nTiles     = (N + 63) / 64;

    // ---- CSR build ----
    hipMemsetAsync(deg, 0, (size_t)N * sizeof(int), stream);
    hipMemsetAsync(cursor, 0, (size_t)N * sizeof(int), stream);
    edge_hist<<<edge_grid, 256, 0, stream>>>(ei, deg, E, ET);
    scan_block<<<nb, 256, 0, stream>>>(deg, excl, bsum, N);
    scan_sums<<<1, 256, 0, stream>>>(bsum, nb);
    scan_final<<<(N + 256) / 256, 256, 0, stream>>>(excl, bsum, rowptr, N, ET);
    edge_fill<<<edge_grid, 256, 0, stream>>>(ei, rowptr, cursor, srcs, E, ET);

    // ---- 3 GATv2 layers ----
    const float* hin = x;
    for (int l = 0; l < 3; ++l) {
        node_gemm<<<nTiles, 256, 0, stream>>>(hin, Wl[l], Wr[l], xlb, xr, N, nTiles);
        gatv2_aggregate<<<node_grid4, 256, 0, stream>>>(
            xlb, xr, rowptr, srcs, att[l], bb[l], hbuf, N, l < 2 ? 1 : 0);
        hin = hbuf;
    }

    // ---- pool + head ----
    graph_bounds<<<1, 256, 0, stream>>>(batch, gstart, N, B);
    hipMemsetAsync(pooled, 0, (size_t)B * 128 * sizeof(float), stream);
    pool_graph<<<B * POOL_CHUNKS, 256, 0, stream>>>(hbuf, gstart, pooled);
    mlp_head<<<B, 256, 0, stream>>>(pooled, gstart, day, hour, day_tab, hour_tab,
                                    W1, bl1, W2, bl2, W3, bl3, out);
}